// Round 2
// baseline (671.215 us; speedup 1.0000x reference)
//
#include <hip/hip_runtime.h>
#include <hip/hip_cooperative_groups.h>

namespace cg = cooperative_groups;

#define BS   256
#define GRID 2048   // 8 blocks/CU x 256 CU: exactly one resident generation (VGPR<=64 via launch_bounds)
#define NB3  2048   // fallback add blocks

typedef float vfloat4 __attribute__((ext_vector_type(4)));

// ---------------- fused cooperative kernel (bit-identical math to 3-kernel path) ----
// P1: identical to reduce_kernel at 2048 blocks (same stride/order -> bit-exact partials)
// grid.sync()
// P2: block 0 alone runs the exact middle_kernel body -> bit-exact r (no redundancy)
// grid.sync()
// P3: identical to add_kernel at 2048 blocks
__global__ void __launch_bounds__(BS, 8) fused_kernel(
    const float* __restrict__ x, const float* __restrict__ w,
    const float* __restrict__ W_in, const float* __restrict__ W_out,
    float* __restrict__ out, float* __restrict__ colpart,
    float* __restrict__ wpart, float* __restrict__ r, long long total4) {
  const int tid = threadIdx.x;
  __shared__ vfloat4 sacc[BS];
  __shared__ float   swr[BS];
  __shared__ float   avg[32];
  __shared__ float   h[128];

  // ---- P1: weighted column partials (== reduce_kernel, gridDim.x == 2048) ----
  {
    const long long stride2 = (long long)GRID * (2 * BS);
    const vfloat4* x4 = (const vfloat4*)x;
    vfloat4 a0 = (vfloat4)(0.f), a1 = (vfloat4)(0.f);
    float w0 = 0.f, w1 = 0.f;
    long long c = (long long)blockIdx.x * (2 * BS) + tid;
    for (; c + BS < total4; c += stride2) {
      const float wi0 = w[(int)(c >> 3)];
      const float wi1 = w[(int)((c + BS) >> 3)];
      const vfloat4 v0 = x4[c];
      const vfloat4 v1 = x4[c + BS];
      a0 += wi0 * v0;
      a1 += wi1 * v1;
      w0 += wi0; w1 += wi1;
    }
    if (c < total4) {  // tail: lone chunk without an in-range partner
      const float wi = w[(int)(c >> 3)];
      a0 += wi * x4[c];
      w0 += wi;
    }
    a0 += a1;
    w0 += w1;
    sacc[tid] = a0;
    swr[tid]  = w0;
    __syncthreads();
    for (int s = BS / 2; s >= 8; s >>= 1) {
      if (tid < s) { sacc[tid] += sacc[tid + s]; swr[tid] += swr[tid + s]; }
      __syncthreads();
    }
    if (tid < 8) {
      ((vfloat4*)(colpart + (long long)blockIdx.x * 32))[tid] = sacc[tid];
    }
    if (tid == 0) {
      wpart[blockIdx.x] = swr[0] + swr[1] + swr[2] + swr[3] +
                          swr[4] + swr[5] + swr[6] + swr[7];
    }
  }

  cg::this_grid().sync();  // all partials visible device-wide

  // ---- P2: block 0 only, exact middle_kernel body (nb = GRID) ----
  if (blockIdx.x == 0) {
    {
      const vfloat4* cp4 = (const vfloat4*)colpart;
      vfloat4 acc = (vfloat4)(0.f);
      for (int cb = tid; cb < GRID * 8; cb += BS) acc += cp4[cb];
      sacc[tid] = acc;
    }
    {
      const vfloat4* wp4 = (const vfloat4*)wpart;
      float s = 0.f;
      for (int cb = tid; cb < GRID / 4; cb += BS) {
        vfloat4 v = wp4[cb];
        s += v.x + v.y + v.z + v.w;
      }
      swr[tid] = s;
    }
    __syncthreads();
    for (int s = BS / 2; s >= 8; s >>= 1) {
      if (tid < s) { sacc[tid] += sacc[tid + s]; swr[tid] += swr[tid + s]; }
      __syncthreads();
    }
    if (tid == 0) {
      // wpart counted each w 8x (once per chunk) -> *0.125 (exact)
      swr[0] = (swr[0] + swr[1] + swr[2] + swr[3] +
                swr[4] + swr[5] + swr[6] + swr[7]) * 0.125f;
    }
    __syncthreads();
    if (tid < 32) {
      const float* sflat = (const float*)sacc;
      avg[tid] = sflat[tid] / swr[0];
    }
    __syncthreads();
    if (tid < 128) {
      float a = 0.f;
      for (int k = 0; k < 32; ++k) a = fmaf(W_in[tid * 32 + k], avg[k], a);
      h[tid] = fmaxf(a, 0.f);
    }
    __syncthreads();
    if (tid < 32) {
      float rv = 0.f;
      for (int k = 0; k < 128; ++k) rv = fmaf(W_out[tid * 128 + k], h[k], rv);
      r[tid] = rv;
    }
    __threadfence();  // belt-and-suspenders: r drained before barrier release
  }

  cg::this_grid().sync();  // r visible device-wide

  // ---- P3: out = x + r (== add_kernel, gridDim.x == 2048) ----
  {
    const vfloat4 rr = ((const vfloat4*)r)[tid & 7];  // chunk col-quad == tid&7
    const long long stride2 = (long long)GRID * (2 * BS);
    const vfloat4* x4 = (const vfloat4*)x;
    vfloat4* o4 = (vfloat4*)out;
    long long c = (long long)blockIdx.x * (2 * BS) + tid;
    for (; c + BS < total4; c += stride2) {
      vfloat4 v0 = x4[c] + rr;
      vfloat4 v1 = x4[c + BS] + rr;
      __builtin_nontemporal_store(v0, &o4[c]);
      __builtin_nontemporal_store(v1, &o4[c + BS]);
    }
    if (c < total4) {
      vfloat4 v = x4[c] + rr;
      __builtin_nontemporal_store(v, &o4[c]);
    }
  }
}

// ---------------- fallback path (proven 266 us 3-kernel version) ----------------
__global__ void __launch_bounds__(BS) reduce_kernel(
    const float* __restrict__ x, const float* __restrict__ w,
    float* __restrict__ colpart, float* __restrict__ wpart, long long total4) {
  const int tid = threadIdx.x;
  const long long stride2 = (long long)gridDim.x * (2 * BS);
  const vfloat4* x4 = (const vfloat4*)x;
  vfloat4 a0 = (vfloat4)(0.f);
  vfloat4 a1 = (vfloat4)(0.f);
  float w0 = 0.f, w1 = 0.f;
  long long c = (long long)blockIdx.x * (2 * BS) + tid;
  for (; c + BS < total4; c += stride2) {
    const float wi0 = w[(int)(c >> 3)];
    const float wi1 = w[(int)((c + BS) >> 3)];
    const vfloat4 v0 = x4[c];
    const vfloat4 v1 = x4[c + BS];
    a0 += wi0 * v0;
    a1 += wi1 * v1;
    w0 += wi0; w1 += wi1;
  }
  if (c < total4) {
    const float wi = w[(int)(c >> 3)];
    a0 += wi * x4[c];
    w0 += wi;
  }
  a0 += a1;
  w0 += w1;
  __shared__ vfloat4 sacc[BS];
  __shared__ float   sw[BS];
  sacc[tid] = a0;
  sw[tid] = w0;
  __syncthreads();
  for (int s = BS / 2; s >= 8; s >>= 1) {
    if (tid < s) { sacc[tid] += sacc[tid + s]; sw[tid] += sw[tid + s]; }
    __syncthreads();
  }
  if (tid < 8) ((vfloat4*)(colpart + (long long)blockIdx.x * 32))[tid] = sacc[tid];
  if (tid == 0)
    wpart[blockIdx.x] = sw[0] + sw[1] + sw[2] + sw[3] + sw[4] + sw[5] + sw[6] + sw[7];
}

__global__ void __launch_bounds__(BS) middle_kernel(
    const float* __restrict__ colpart, const float* __restrict__ wpart,
    const float* __restrict__ W_in, const float* __restrict__ W_out,
    float* __restrict__ r_out, int nb) {
  const int tid = threadIdx.x;
  __shared__ vfloat4 sacc[BS];
  __shared__ float   swr[BS];
  __shared__ float   avg[32];
  __shared__ float   h[128];
  {
    const vfloat4* cp4 = (const vfloat4*)colpart;
    const int nchunk = nb * 8;
    vfloat4 acc = (vfloat4)(0.f);
    for (int cb = tid; cb < nchunk; cb += BS) acc += cp4[cb];
    sacc[tid] = acc;
  }
  {
    const vfloat4* wp4 = (const vfloat4*)wpart;
    const int nchunk = nb / 4;
    float s = 0.f;
    for (int cb = tid; cb < nchunk; cb += BS) {
      vfloat4 v = wp4[cb];
      s += v.x + v.y + v.z + v.w;
    }
    swr[tid] = s;
  }
  __syncthreads();
  for (int s = BS / 2; s >= 8; s >>= 1) {
    if (tid < s) { sacc[tid] += sacc[tid + s]; swr[tid] += swr[tid + s]; }
    __syncthreads();
  }
  if (tid == 0) {
    swr[0] = (swr[0] + swr[1] + swr[2] + swr[3] +
              swr[4] + swr[5] + swr[6] + swr[7]) * 0.125f;
  }
  __syncthreads();
  if (tid < 32) {
    const float* sflat = (const float*)sacc;
    avg[tid] = sflat[tid] / swr[0];
  }
  __syncthreads();
  if (tid < 128) {
    float a = 0.f;
    for (int k = 0; k < 32; ++k) a = fmaf(W_in[tid * 32 + k], avg[k], a);
    h[tid] = fmaxf(a, 0.f);
  }
  __syncthreads();
  if (tid < 32) {
    float r = 0.f;
    for (int k = 0; k < 128; ++k) r = fmaf(W_out[tid * 128 + k], h[k], r);
    r_out[tid] = r;
  }
}

__global__ void __launch_bounds__(BS) add_kernel(
    const float* __restrict__ x, const float* __restrict__ r,
    float* __restrict__ out, long long total4) {
  const int tid = threadIdx.x;
  const vfloat4 rr = ((const vfloat4*)r)[tid & 7];
  const long long stride2 = (long long)gridDim.x * (2 * BS);
  const vfloat4* x4 = (const vfloat4*)x;
  vfloat4* o4 = (vfloat4*)out;
  long long c = (long long)blockIdx.x * (2 * BS) + tid;
  for (; c + BS < total4; c += stride2) {
    vfloat4 v0 = x4[c] + rr;
    vfloat4 v1 = x4[c + BS] + rr;
    __builtin_nontemporal_store(v0, &o4[c]);
    __builtin_nontemporal_store(v1, &o4[c + BS]);
  }
  if (c < total4) {
    vfloat4 v = x4[c] + rr;
    __builtin_nontemporal_store(v, &o4[c]);
  }
}

extern "C" void kernel_launch(void* const* d_in, const int* in_sizes, int n_in,
                              void* d_out, int out_size, void* d_ws, size_t ws_size,
                              hipStream_t stream) {
  const float* x     = (const float*)d_in[0];
  const float* w     = (const float*)d_in[1];
  const float* W_in  = (const float*)d_in[2];
  const float* W_out = (const float*)d_in[3];
  float* out = (float*)d_out;

  const long long N = (long long)in_sizes[0] / 32;
  const long long total4 = N * 8;  // float4 chunks (32 floats/row = 8 float4)

  // workspace layout: colpart[GRID*32] | wpart[GRID] | r[32]  (~270 KB)
  float* colpart = (float*)d_ws;
  float* wpart   = colpart + (size_t)GRID * 32;
  float* r       = wpart + GRID;  // 16B-aligned: GRID*33*4 % 16 == 0

  if ((size_t)(GRID * 33 + 32) * 4 <= ws_size) {
    void* args[] = {(void*)&x, (void*)&w, (void*)&W_in, (void*)&W_out,
                    (void*)&out, (void*)&colpart, (void*)&wpart, (void*)&r,
                    (void*)&total4};
    hipError_t err = hipLaunchCooperativeKernel((const void*)fused_kernel,
                                                dim3(GRID), dim3(BS), args, 0, stream);
    if (err == hipSuccess) return;
  }

  // fallback: proven 3-kernel path
  int nb = GRID;
  while (nb > 64 && (size_t)(nb * 33 + 32) * 4 > ws_size) nb >>= 1;
  reduce_kernel<<<nb, BS, 0, stream>>>(x, w, colpart, wpart, total4);
  middle_kernel<<<1, BS, 0, stream>>>(colpart, wpart, W_in, W_out, r, nb);
  add_kernel<<<NB3, BS, 0, stream>>>(x, r, out, total4);
}

// Round 4
// 358.779 us; speedup vs baseline: 1.8708x; 1.8708x over previous
//
#include <hip/hip_runtime.h>

#define BS   256
#define NB1  2048   // reduction blocks (8/CU) — partials = NB1*33 floats in d_ws
#define NB3  2048   // add blocks

typedef float vfloat4 __attribute__((ext_vector_type(4)));

// Kernel A: block-partial weighted column sums (identical math/order to the
// proven 266us reduce_kernel), then the LAST block to finish (device-scope
// ticket) runs the exact middle_kernel body -> bit-identical r.
// No spinning: non-last blocks exit immediately (vs cooperative grid.sync,
// which measured 300+us of barrier overhead at 2048 blocks in round 2).
__global__ void __launch_bounds__(BS) reduce_mid_kernel(
    const float* __restrict__ x, const float* __restrict__ w,
    const float* __restrict__ W_in, const float* __restrict__ W_out,
    float* __restrict__ colpart, float* __restrict__ wpart,
    float* __restrict__ r_out, unsigned* __restrict__ ticket,
    long long total4) {
  const int tid = threadIdx.x;
  __shared__ vfloat4 sacc[BS];
  __shared__ float   swr[BS];
  __shared__ float   avg[32];
  __shared__ float   h[128];
  __shared__ bool    is_last;

  // ---- reduce phase (bit-identical to proven reduce_kernel @ 2048 blocks) ----
  {
    const long long stride2 = (long long)gridDim.x * (2 * BS);
    const vfloat4* x4 = (const vfloat4*)x;
    vfloat4 a0 = (vfloat4)(0.f), a1 = (vfloat4)(0.f);
    float w0 = 0.f, w1 = 0.f;
    long long c = (long long)blockIdx.x * (2 * BS) + tid;
    for (; c + BS < total4; c += stride2) {
      const float wi0 = w[(int)(c >> 3)];
      const float wi1 = w[(int)((c + BS) >> 3)];
      const vfloat4 v0 = x4[c];
      const vfloat4 v1 = x4[c + BS];
      a0 += wi0 * v0;
      a1 += wi1 * v1;
      w0 += wi0; w1 += wi1;
    }
    if (c < total4) {  // tail: lone chunk without an in-range partner
      const float wi = w[(int)(c >> 3)];
      a0 += wi * x4[c];
      w0 += wi;
    }
    a0 += a1;
    w0 += w1;
    sacc[tid] = a0;
    swr[tid]  = w0;
    __syncthreads();
    // tree-reduce; stop at s=8 so column groups (tid&7) stay separated
    for (int s = BS / 2; s >= 8; s >>= 1) {
      if (tid < s) { sacc[tid] += sacc[tid + s]; swr[tid] += swr[tid + s]; }
      __syncthreads();
    }
    if (tid < 8) {
      ((vfloat4*)(colpart + (long long)blockIdx.x * 32))[tid] = sacc[tid];
    }
    if (tid == 0) {
      wpart[blockIdx.x] = swr[0] + swr[1] + swr[2] + swr[3] +
                          swr[4] + swr[5] + swr[6] + swr[7];
    }
  }

  // ---- last-block ticket (release: partials visible before the ticket) ----
  if (tid == 0) {
    __threadfence();                         // publish colpart/wpart device-wide
    unsigned prev = atomicAdd(ticket, 1u);   // device-scope by default
    is_last = (prev == gridDim.x - 1);
  }
  __syncthreads();
  if (!is_last) return;
  __threadfence();                           // acquire: see all partials

  // ---- middle phase (exact middle_kernel body, nb = gridDim.x) ----
  {
    const vfloat4* cp4 = (const vfloat4*)colpart;
    const int nchunk = (int)gridDim.x * 8;
    vfloat4 acc = (vfloat4)(0.f);
    for (int cb = tid; cb < nchunk; cb += BS) acc += cp4[cb];
    sacc[tid] = acc;
  }
  {
    const vfloat4* wp4 = (const vfloat4*)wpart;
    const int nchunk = (int)gridDim.x / 4;
    float s = 0.f;
    for (int cb = tid; cb < nchunk; cb += BS) {
      vfloat4 v = wp4[cb];
      s += v.x + v.y + v.z + v.w;
    }
    swr[tid] = s;
  }
  __syncthreads();
  for (int s = BS / 2; s >= 8; s >>= 1) {
    if (tid < s) { sacc[tid] += sacc[tid + s]; swr[tid] += swr[tid + s]; }
    __syncthreads();
  }
  if (tid == 0) {
    // wpart counted each w 8x (once per chunk) -> *0.125 (exact)
    swr[0] = (swr[0] + swr[1] + swr[2] + swr[3] +
              swr[4] + swr[5] + swr[6] + swr[7]) * 0.125f;
  }
  __syncthreads();
  if (tid < 32) {
    // column j lives in sacc[j>>2] component j&3
    const float* sflat = (const float*)sacc;
    avg[tid] = sflat[tid] / swr[0];
  }
  __syncthreads();
  if (tid < 128) {
    float a = 0.f;
    for (int k = 0; k < 32; ++k) a = fmaf(W_in[tid * 32 + k], avg[k], a);
    h[tid] = fmaxf(a, 0.f);
  }
  __syncthreads();
  if (tid < 32) {
    float r = 0.f;
    for (int k = 0; k < 128; ++k) r = fmaf(W_out[tid * 128 + k], h[k], r);
    r_out[tid] = r;
  }
}

// Kernel B: out[i][j] = x[i][j] + r[j]; x read (L3-warm), out via NT stores.
__global__ void __launch_bounds__(BS) add_kernel(
    const float* __restrict__ x, const float* __restrict__ r,
    float* __restrict__ out, long long total4) {
  const int tid = threadIdx.x;
  const vfloat4 rr = ((const vfloat4*)r)[tid & 7];  // chunk col-quad == tid&7
  const long long stride2 = (long long)gridDim.x * (2 * BS);
  const vfloat4* x4 = (const vfloat4*)x;
  vfloat4* o4 = (vfloat4*)out;
  long long c = (long long)blockIdx.x * (2 * BS) + tid;
  for (; c + BS < total4; c += stride2) {
    vfloat4 v0 = x4[c] + rr;
    vfloat4 v1 = x4[c + BS] + rr;
    __builtin_nontemporal_store(v0, &o4[c]);
    __builtin_nontemporal_store(v1, &o4[c + BS]);
  }
  if (c < total4) {
    vfloat4 v = x4[c] + rr;
    __builtin_nontemporal_store(v, &o4[c]);
  }
}

extern "C" void kernel_launch(void* const* d_in, const int* in_sizes, int n_in,
                              void* d_out, int out_size, void* d_ws, size_t ws_size,
                              hipStream_t stream) {
  const float* x     = (const float*)d_in[0];
  const float* w     = (const float*)d_in[1];
  const float* W_in  = (const float*)d_in[2];
  const float* W_out = (const float*)d_in[3];
  float* out = (float*)d_out;

  const long long N = (long long)in_sizes[0] / 32;
  const long long total4 = N * 8;  // float4 chunks (32 floats/row = 8 float4)

  // workspace layout: colpart[nb*32] | wpart[nb] | r[32] | ticket[1]
  int nb = NB1;
  while (nb > 64 && (size_t)(nb * 33 + 33) * 4 > ws_size) nb >>= 1;
  float* colpart  = (float*)d_ws;
  float* wpart    = colpart + (size_t)nb * 32;
  float* r        = wpart + nb;      // 16B-aligned: nb*33*4 % 16 == 0 for nb%4==0
  unsigned* ticket = (unsigned*)(r + 32);

  // ticket must start at 0 each iteration (workspace is re-poisoned by harness;
  // hipMemsetAsync is stream-capture-legal — the harness reset() uses it too)
  hipMemsetAsync(ticket, 0, sizeof(unsigned), stream);
  reduce_mid_kernel<<<nb, BS, 0, stream>>>(x, w, W_in, W_out, colpart, wpart,
                                           r, ticket, total4);
  add_kernel<<<NB3, BS, 0, stream>>>(x, r, out, total4);
}

// Round 5
// 264.985 us; speedup vs baseline: 2.5330x; 1.3540x over previous
//
#include <hip/hip_runtime.h>

#define BS 256
#define NB1 2048   // reduction blocks (8/CU) — partials = NB1*33 floats in d_ws
#define NB3 2048   // add blocks

typedef float vfloat4 __attribute__((ext_vector_type(4)));

// Pass 1: colpart[b*32+j] = block-partial of sum_i w_i * x[i][j], wpart[b] =
// 8 * block-partial of sum_i w_i (each row's w counted once per float4 chunk,
// i.e. 8x; corrected by *0.125 in middle_kernel — exact binary scaling).
// Chunk c has column group c%8 == tid%8 (all strides are multiples of 8).
__global__ void __launch_bounds__(BS) reduce_kernel(
    const float* __restrict__ x, const float* __restrict__ w,
    float* __restrict__ colpart, float* __restrict__ wpart, long long total4) {
  const int tid = threadIdx.x;
  const long long stride2 = (long long)gridDim.x * (2 * BS);
  const vfloat4* x4 = (const vfloat4*)x;
  vfloat4 a0 = (vfloat4)(0.f);
  vfloat4 a1 = (vfloat4)(0.f);
  float w0 = 0.f, w1 = 0.f;
  long long c = (long long)blockIdx.x * (2 * BS) + tid;
  for (; c + BS < total4; c += stride2) {
    const float wi0 = w[(int)(c >> 3)];
    const float wi1 = w[(int)((c + BS) >> 3)];
    const vfloat4 v0 = x4[c];
    const vfloat4 v1 = x4[c + BS];
    a0 += wi0 * v0;
    a1 += wi1 * v1;
    w0 += wi0; w1 += wi1;
  }
  if (c < total4) {  // tail: lone chunk without an in-range partner
    const float wi = w[(int)(c >> 3)];
    a0 += wi * x4[c];
    w0 += wi;
  }
  a0 += a1;
  w0 += w1;
  __shared__ vfloat4 sacc[BS];
  __shared__ float   sw[BS];
  sacc[tid] = a0;
  sw[tid] = w0;
  __syncthreads();
  // tree-reduce; stop at s=8 so column groups (tid&7) stay separated
  for (int s = BS / 2; s >= 8; s >>= 1) {
    if (tid < s) {
      sacc[tid] += sacc[tid + s];
      sw[tid] += sw[tid + s];
    }
    __syncthreads();
  }
  if (tid < 8) {
    ((vfloat4*)(colpart + (long long)blockIdx.x * 32))[tid] = sacc[tid];
  }
  if (tid == 0) {
    wpart[blockIdx.x] = sw[0] + sw[1] + sw[2] + sw[3] +
                        sw[4] + sw[5] + sw[6] + sw[7];
  }
}

// Stage 2 (single block): finish reduction, r = W_out @ relu(W_in @ avg)
__global__ void __launch_bounds__(BS) middle_kernel(
    const float* __restrict__ colpart, const float* __restrict__ wpart,
    const float* __restrict__ W_in, const float* __restrict__ W_out,
    float* __restrict__ r_out, int nb) {
  const int tid = threadIdx.x;
  __shared__ vfloat4 sacc[BS];
  __shared__ float   swr[BS];
  __shared__ float   avg[32];
  __shared__ float   h[128];
  // column partials: colpart as vfloat4; chunk's column-quad = cb&7 == tid&7
  {
    const vfloat4* cp4 = (const vfloat4*)colpart;
    const int nchunk = nb * 8;
    vfloat4 acc = (vfloat4)(0.f);
    for (int cb = tid; cb < nchunk; cb += BS) acc += cp4[cb];
    sacc[tid] = acc;
  }
  {
    const vfloat4* wp4 = (const vfloat4*)wpart;
    const int nchunk = nb / 4;
    float s = 0.f;
    for (int cb = tid; cb < nchunk; cb += BS) {
      vfloat4 v = wp4[cb];
      s += v.x + v.y + v.z + v.w;
    }
    swr[tid] = s;
  }
  __syncthreads();
  for (int s = BS / 2; s >= 8; s >>= 1) {
    if (tid < s) {
      sacc[tid] += sacc[tid + s];
      swr[tid] += swr[tid + s];
    }
    __syncthreads();
  }
  if (tid == 0) {
    // wpart counted each w 8x (once per chunk) -> *0.125 (exact)
    float wsum = (swr[0] + swr[1] + swr[2] + swr[3] +
                  swr[4] + swr[5] + swr[6] + swr[7]) * 0.125f;
    swr[0] = wsum;
  }
  __syncthreads();
  if (tid < 32) {
    // column j lives in sacc[j>>2] component j&3
    const float* sflat = (const float*)sacc;
    avg[tid] = sflat[tid] / swr[0];
  }
  __syncthreads();
  if (tid < 128) {
    float a = 0.f;
    for (int k = 0; k < 32; ++k) a = fmaf(W_in[tid * 32 + k], avg[k], a);
    h[tid] = fmaxf(a, 0.f);
  }
  __syncthreads();
  if (tid < 32) {
    float r = 0.f;
    for (int k = 0; k < 128; ++k) r = fmaf(W_out[tid * 128 + k], h[k], r);
    r_out[tid] = r;
  }
}

// Pass 2: out[i][j] = x[i][j] + r[j]; x read (L3-warm), out via NT stores.
__global__ void __launch_bounds__(BS) add_kernel(
    const float* __restrict__ x, const float* __restrict__ r,
    float* __restrict__ out, long long total4) {
  const int tid = threadIdx.x;
  const vfloat4 rr = ((const vfloat4*)r)[tid & 7];  // chunk col-quad == tid&7
  const long long stride2 = (long long)gridDim.x * (2 * BS);
  const vfloat4* x4 = (const vfloat4*)x;
  vfloat4* o4 = (vfloat4*)out;
  long long c = (long long)blockIdx.x * (2 * BS) + tid;
  for (; c + BS < total4; c += stride2) {
    vfloat4 v0 = x4[c] + rr;
    vfloat4 v1 = x4[c + BS] + rr;
    __builtin_nontemporal_store(v0, &o4[c]);
    __builtin_nontemporal_store(v1, &o4[c + BS]);
  }
  if (c < total4) {
    vfloat4 v = x4[c] + rr;
    __builtin_nontemporal_store(v, &o4[c]);
  }
}

extern "C" void kernel_launch(void* const* d_in, const int* in_sizes, int n_in,
                              void* d_out, int out_size, void* d_ws, size_t ws_size,
                              hipStream_t stream) {
  const float* x     = (const float*)d_in[0];
  const float* w     = (const float*)d_in[1];
  const float* W_in  = (const float*)d_in[2];
  const float* W_out = (const float*)d_in[3];
  float* out = (float*)d_out;

  const long long N = (long long)in_sizes[0] / 32;
  const long long total4 = N * 8;  // float4 chunks (32 floats/row = 8 float4)

  // workspace layout: colpart[nb*32] | wpart[nb] | r[32]
  int nb = NB1;
  while (nb > 64 && (size_t)(nb * 33 + 32) * 4 > ws_size) nb >>= 1;
  float* colpart = (float*)d_ws;
  float* wpart   = colpart + (size_t)nb * 32;
  float* r       = wpart + nb;  // 16B-aligned: nb*33*4 % 16 == 0 for nb%4==0

  reduce_kernel<<<nb, BS, 0, stream>>>(x, w, colpart, wpart, total4);
  middle_kernel<<<1, BS, 0, stream>>>(colpart, wpart, W_in, W_out, r, nb);
  add_kernel<<<NB3, BS, 0, stream>>>(x, r, out, total4);
}